// Round 1
// baseline (699.310 us; speedup 1.0000x reference)
//
#include <hip/hip_runtime.h>
#include <cstdint>
#include <cstddef>

typedef __attribute__((ext_vector_type(8))) short bhalf8;   // 8 bf16 in 4 VGPRs
typedef __attribute__((ext_vector_type(4))) float f32x4;

__device__ __forceinline__ unsigned short f2bf(float f){
    unsigned int u = __float_as_uint(f);
    u += 0x7fffu + ((u >> 16) & 1u);          // round-to-nearest-even
    return (unsigned short)(u >> 16);
}

__device__ __forceinline__ float gelu_tanh(float x){
    const float c0 = 0.7978845608028654f;      // sqrt(2/pi)
    float x3 = x * x * x;
    float t = tanhf(c0 * (x + 0.044715f * x3));
    return 0.5f * x * (1.0f + t);
}

// ---------------------------------------------------------------------------
// Top-k(32) of 256 logits + softmax weights. blockIdx.x selects logits set.
// One wave (64 lanes), each lane owns 4 entries; 32 iterative argmax rounds.
// ---------------------------------------------------------------------------
__global__ void topk_softmax_kernel(const float* __restrict__ lg1,
                                    const float* __restrict__ lg2,
                                    int* __restrict__ idx_out,
                                    float* __restrict__ w_out)
{
    const float* lg = (blockIdx.x == 0) ? lg1 : lg2;
    int*   idxo = idx_out + blockIdx.x * 32;
    float* wo   = w_out   + blockIdx.x * 32;
    const int lane = threadIdx.x;       // 0..63
    float v[4];
    #pragma unroll
    for (int j = 0; j < 4; ++j) v[j] = lg[lane * 4 + j];
    __shared__ float svals[32];
    for (int k = 0; k < 32; ++k){
        float bv = -1e30f; int bi = 0;
        #pragma unroll
        for (int j = 0; j < 4; ++j){
            if (v[j] > bv){ bv = v[j]; bi = lane * 4 + j; }
        }
        for (int off = 32; off > 0; off >>= 1){
            float ov = __shfl_down(bv, off);
            int   oi = __shfl_down(bi, off);
            if (ov > bv){ bv = ov; bi = oi; }
        }
        bv = __shfl(bv, 0);
        bi = __shfl(bi, 0);
        if (lane == 0){ svals[k] = bv; idxo[k] = bi; }
        if ((bi >> 2) == lane) v[bi & 3] = -1e30f;   // remove selected
    }
    if (lane == 0){
        float mx = svals[0];            // first pick is the max
        float sum = 0.f;
        for (int k = 0; k < 32; ++k){ float e = expf(svals[k] - mx); wo[k] = e; sum += e; }
        float inv = 1.f / sum;
        for (int k = 0; k < 32; ++k) wo[k] *= inv;
    }
}

// ---------------------------------------------------------------------------
// x (fp32) -> bf16
// ---------------------------------------------------------------------------
__global__ void convert_bf16_kernel(const float* __restrict__ src,
                                    unsigned short* __restrict__ dst, int n4)
{
    int v = blockIdx.x * 256 + threadIdx.x;
    if (v >= n4) return;
    float4 x = ((const float4*)src)[v];
    ushort4 o; o.x = f2bf(x.x); o.y = f2bf(x.y); o.z = f2bf(x.z); o.w = f2bf(x.w);
    ((ushort4*)dst)[v] = o;
}

// ---------------------------------------------------------------------------
// Natural gather: dst[d, k*64+r] = scale_k * src[idx_k, d, r]
// src: (P, Drows, 64) fp32; dst: (Drows, 2048) bf16 row-major (K-major).
// ---------------------------------------------------------------------------
__global__ void gather_nat_kernel(const float* __restrict__ src,
                                  unsigned short* __restrict__ dst,
                                  const int* __restrict__ idx,
                                  const float* __restrict__ w,
                                  int Drows, int use_scale, int n4)
{
    int v = blockIdx.x * 256 + threadIdx.x;  // float4 index
    if (v >= n4) return;
    int c4 = v & 511;          // 512 float4 per dst row (2048 cols)
    int d  = v >> 9;
    int k  = c4 >> 4;          // expert slot 0..31
    int r4 = c4 & 15;          // float4 within r-dim (64)
    int p  = idx[k];
    float sc = use_scale ? w[k] : 1.0f;
    const float4* s = (const float4*)(src + ((size_t)p * Drows + d) * 64) + r4;
    float4 x = *s;
    ushort4 o;
    o.x = f2bf(sc * x.x); o.y = f2bf(sc * x.y);
    o.z = f2bf(sc * x.z); o.w = f2bf(sc * x.w);
    *(ushort4*)(dst + (size_t)d * 2048 + k * 64 + r4 * 4) = o;
}

// ---------------------------------------------------------------------------
// Transposed gather: dst[f, k*64+r] = scale_k * src[idx_k, r, f]
// src: (P, 64, Fcols) fp32; dst: (Fcols, 2048) bf16 row-major (K-major).
// One block per (64-wide f tile, expert slot): 64x64 transpose via LDS.
// ---------------------------------------------------------------------------
__global__ void gather_tr_kernel(const float* __restrict__ src,
                                 unsigned short* __restrict__ dst,
                                 const int* __restrict__ idx,
                                 const float* __restrict__ w,
                                 int Fcols, int use_scale)
{
    const int k  = blockIdx.y;
    const int f0 = blockIdx.x * 64;
    const int p  = idx[k];
    const float sc = use_scale ? w[k] : 1.0f;
    __shared__ float tile[64][65];
    const int t  = threadIdx.x;       // 256
    const int cf = t & 15;            // float4 column
    const int r0 = t >> 4;            // 16 rows per pass
    #pragma unroll
    for (int pass = 0; pass < 4; ++pass){
        int r = r0 + pass * 16;
        float4 x = *((const float4*)(src + ((size_t)p * 64 + r) * Fcols + f0) + cf);
        tile[r][cf * 4 + 0] = x.x; tile[r][cf * 4 + 1] = x.y;
        tile[r][cf * 4 + 2] = x.z; tile[r][cf * 4 + 3] = x.w;
    }
    __syncthreads();
    const int r4  = t & 15;           // float4 within r-dim
    const int fl0 = t >> 4;
    #pragma unroll
    for (int pass = 0; pass < 4; ++pass){
        int fl = fl0 + pass * 16;
        ushort4 o;
        o.x = f2bf(sc * tile[r4 * 4 + 0][fl]);
        o.y = f2bf(sc * tile[r4 * 4 + 1][fl]);
        o.z = f2bf(sc * tile[r4 * 4 + 2][fl]);
        o.w = f2bf(sc * tile[r4 * 4 + 3][fl]);
        *(ushort4*)(dst + (size_t)(f0 + fl) * 2048 + k * 64 + r4 * 4) = o;
    }
}

// ---------------------------------------------------------------------------
// NT bf16 GEMM: C(M,N) = A(M,K) * Bt(N,K)^T, fp32 accumulate.
// 128x128 block tile, BK=32, 4 waves each computing 64x64 via 4x4 of
// v_mfma_f32_16x16x32_bf16. EPI: 0 = bf16 store, 1 = gelu+bf16, 2 = fp32.
// ---------------------------------------------------------------------------
template<int EPI>
__launch_bounds__(256, 2)
__global__ void gemm_nt_kernel(const unsigned short* __restrict__ A,
                               const unsigned short* __restrict__ Bt,
                               void* __restrict__ Cout,
                               int M, int N, int K)
{
    __shared__ unsigned short sA[128 * 32];
    __shared__ unsigned short sB[128 * 32];
    const int bm = blockIdx.y * 128;
    const int bn = blockIdx.x * 128;
    const int t    = threadIdx.x;
    const int wave = t >> 6;
    const int lane = t & 63;
    const int wr   = (wave >> 1) * 64;   // wave row offset in tile
    const int wc   = (wave & 1) * 64;    // wave col offset in tile
    const int m16  = lane & 15;
    const int quad = lane >> 4;
    const int srow = t >> 2;             // staging row (64 rows/pass)
    const int scol = t & 3;              // staging 16B chunk within 64B row

    f32x4 acc[4][4];
    const f32x4 z = {0.f, 0.f, 0.f, 0.f};
    #pragma unroll
    for (int i = 0; i < 4; ++i)
        #pragma unroll
        for (int j = 0; j < 4; ++j) acc[i][j] = z;

    const unsigned short* Arow = A  + (size_t)(bm + srow) * K + scol * 8;
    const unsigned short* Brow = Bt + (size_t)(bn + srow) * K + scol * 8;

    for (int k0 = 0; k0 < K; k0 += 32){
        *(bhalf8*)(sA + srow * 32 + scol * 8)        = *(const bhalf8*)(Arow + k0);
        *(bhalf8*)(sA + (srow + 64) * 32 + scol * 8) = *(const bhalf8*)(Arow + (size_t)64 * K + k0);
        *(bhalf8*)(sB + srow * 32 + scol * 8)        = *(const bhalf8*)(Brow + k0);
        *(bhalf8*)(sB + (srow + 64) * 32 + scol * 8) = *(const bhalf8*)(Brow + (size_t)64 * K + k0);
        __syncthreads();

        bhalf8 af[4], bfr[4];
        #pragma unroll
        for (int i = 0; i < 4; ++i)
            af[i] = *(const bhalf8*)(sA + (wr + i * 16 + m16) * 32 + quad * 8);
        #pragma unroll
        for (int j = 0; j < 4; ++j)
            bfr[j] = *(const bhalf8*)(sB + (wc + j * 16 + m16) * 32 + quad * 8);

        #pragma unroll
        for (int i = 0; i < 4; ++i)
            #pragma unroll
            for (int j = 0; j < 4; ++j)
                acc[i][j] = __builtin_amdgcn_mfma_f32_16x16x32_bf16(af[i], bfr[j], acc[i][j], 0, 0, 0);
        __syncthreads();
    }

    // Epilogue. C/D layout: col = lane&15, row = quad*4 + reg  [m89/m91]
    #pragma unroll
    for (int i = 0; i < 4; ++i){
        #pragma unroll
        for (int j = 0; j < 4; ++j){
            #pragma unroll
            for (int r = 0; r < 4; ++r){
                int row = bm + wr + i * 16 + quad * 4 + r;
                int col = bn + wc + j * 16 + m16;
                float vv = acc[i][j][r];
                if (EPI == 1) vv = gelu_tanh(vv);
                if (EPI == 2) ((float*)Cout)[(size_t)row * N + col] = vv;
                else ((unsigned short*)Cout)[(size_t)row * N + col] = f2bf(vv);
            }
        }
    }
}

// ---------------------------------------------------------------------------
extern "C" void kernel_launch(void* const* d_in, const int* in_sizes, int n_in,
                              void* d_out, int out_size, void* d_ws, size_t ws_size,
                              hipStream_t stream)
{
    const float* x    = (const float*)d_in[0];   // (2,1024,1024)
    const float* fc1A = (const float*)d_in[1];   // (256,1024,64)
    const float* fc1B = (const float*)d_in[2];   // (256,64,4096)
    const float* fc2A = (const float*)d_in[3];   // (256,4096,64)
    const float* fc2B = (const float*)d_in[4];   // (256,64,1024)
    const float* lg1  = (const float*)d_in[5];   // (256,)
    const float* lg2  = (const float*)d_in[6];   // (256,)
    float* out = (float*)d_out;                  // (2,1024,1024) fp32

    char* ws = (char*)d_ws;
    // workspace layout (48 MB + 4 KB)
    int*            idxb = (int*)(ws + 0);                    // [64]
    float*          wb   = (float*)(ws + 256);                // [64]
    unsigned short* x16  = (unsigned short*)(ws + 4096);                      // 4 MB  (2048x1024)
    unsigned short* Ag1  = (unsigned short*)(ws + 4096 + (4u << 20));         // 4 MB  (1024x2048)
    unsigned short* Bt1  = (unsigned short*)(ws + 4096 + (8u << 20));         // 16 MB (4096x2048)
    unsigned short* W1t  = (unsigned short*)(ws + 4096 + (24u << 20));        // 8 MB  (4096x1024)
    unsigned short* hbuf = (unsigned short*)(ws + 4096 + (32u << 20));        // 16 MB (2048x4096)
    unsigned short* Ag2  = Bt1;   // reuse: dead after GEMM1 (4096x2048)
    unsigned short* Bg2t = Ag1;   // reuse: dead after GEMM1 (1024x2048)
    unsigned short* W2t  = W1t;   // reuse: W1t dead after GEMM2 (1024x4096)

    // 1. top-k + softmax for both layers
    topk_softmax_kernel<<<dim3(2), dim3(64), 0, stream>>>(lg1, lg2, idxb, wb);

    // 2. x -> bf16  (2048*1024/4 = 524288 float4)
    convert_bf16_kernel<<<dim3(2048), dim3(256), 0, stream>>>(x, x16, 524288);

    // 3. gathers for layer 1: Ag1[d,kr] = w_k*fc1A[p,d,r]; Bt1[f,kr] = fc1B[p,r,f]
    gather_nat_kernel<<<dim3(2048), dim3(256), 0, stream>>>(fc1A, Ag1, idxb, wb, 1024, 1, 524288);
    gather_tr_kernel<<<dim3(64, 32), dim3(256), 0, stream>>>(fc1B, Bt1, idxb, wb, 4096, 0);

    // 4. GEMM1: W1t(4096x1024) = Bt1(4096x2048) * Ag1(1024x2048)^T
    gemm_nt_kernel<0><<<dim3(8, 32), dim3(256), 0, stream>>>(Bt1, Ag1, W1t, 4096, 1024, 2048);

    // 5. GEMM2: h(2048x4096) = gelu( x16(2048x1024) * W1t(4096x1024)^T )
    gemm_nt_kernel<1><<<dim3(32, 16), dim3(256), 0, stream>>>(x16, W1t, hbuf, 2048, 4096, 1024);

    // 6. gathers for layer 2: Ag2[f,kr] = fc2A[p,f,r]; Bg2t[d,kr] = w_k*fc2B[p,r,d]
    gather_nat_kernel<<<dim3(8192), dim3(256), 0, stream>>>(fc2A, Ag2, idxb + 32, wb + 32, 4096, 0, 2097152);
    gather_tr_kernel<<<dim3(16, 32), dim3(256), 0, stream>>>(fc2B, Bg2t, idxb + 32, wb + 32, 1024, 1);

    // 7. GEMM3: W2t(1024x4096) = Bg2t(1024x2048) * Ag2(4096x2048)^T
    gemm_nt_kernel<0><<<dim3(32, 8), dim3(256), 0, stream>>>(Bg2t, Ag2, W2t, 1024, 4096, 2048);

    // 8. GEMM4: out(2048x1024) = h(2048x4096) * W2t(1024x4096)^T   (fp32 store)
    gemm_nt_kernel<2><<<dim3(8, 16), dim3(256), 0, stream>>>(hbuf, W2t, out, 2048, 1024, 4096);
}

// Round 2
// 664.664 us; speedup vs baseline: 1.0521x; 1.0521x over previous
//
#include <hip/hip_runtime.h>
#include <cstdint>
#include <cstddef>

typedef __attribute__((ext_vector_type(8))) short bhalf8;   // 8 bf16 in 4 VGPRs
typedef __attribute__((ext_vector_type(4))) float f32x4;

__device__ __forceinline__ unsigned short f2bf(float f){
    unsigned int u = __float_as_uint(f);
    u += 0x7fffu + ((u >> 16) & 1u);          // round-to-nearest-even
    return (unsigned short)(u >> 16);
}

__device__ __forceinline__ float gelu_tanh(float x){
    const float c0 = 0.7978845608028654f;      // sqrt(2/pi)
    float x3 = x * x * x;
    float t = tanhf(c0 * (x + 0.044715f * x3));
    return 0.5f * x * (1.0f + t);
}

// async global->LDS, 16B per lane. LDS dest is wave-uniform base + lane*16;
// caller must pass a per-thread pointer whose byte offset == t*16 within the
// staging region so readfirstlane(base)+lane*16 matches every lane's intent.
__device__ __forceinline__ void async_lds16(const unsigned short* g, unsigned short* l){
    __builtin_amdgcn_global_load_lds(
        (const __attribute__((address_space(1))) void*)g,
        (__attribute__((address_space(3))) void*)l, 16, 0, 0);
}

// ---------------------------------------------------------------------------
// Top-k(32) of 256 logits + softmax weights. blockIdx.x selects logits set.
// ---------------------------------------------------------------------------
__global__ void topk_softmax_kernel(const float* __restrict__ lg1,
                                    const float* __restrict__ lg2,
                                    int* __restrict__ idx_out,
                                    float* __restrict__ w_out)
{
    const float* lg = (blockIdx.x == 0) ? lg1 : lg2;
    int*   idxo = idx_out + blockIdx.x * 32;
    float* wo   = w_out   + blockIdx.x * 32;
    const int lane = threadIdx.x;       // 0..63
    float v[4];
    #pragma unroll
    for (int j = 0; j < 4; ++j) v[j] = lg[lane * 4 + j];
    __shared__ float svals[32];
    for (int k = 0; k < 32; ++k){
        float bv = -1e30f; int bi = 0;
        #pragma unroll
        for (int j = 0; j < 4; ++j){
            if (v[j] > bv){ bv = v[j]; bi = lane * 4 + j; }
        }
        for (int off = 32; off > 0; off >>= 1){
            float ov = __shfl_down(bv, off);
            int   oi = __shfl_down(bi, off);
            if (ov > bv){ bv = ov; bi = oi; }
        }
        bv = __shfl(bv, 0);
        bi = __shfl(bi, 0);
        if (lane == 0){ svals[k] = bv; idxo[k] = bi; }
        if ((bi >> 2) == lane) v[bi & 3] = -1e30f;   // remove selected
    }
    if (lane == 0){
        float mx = svals[0];            // first pick is the max
        float sum = 0.f;
        for (int k = 0; k < 32; ++k){ float e = expf(svals[k] - mx); wo[k] = e; sum += e; }
        float inv = 1.f / sum;
        for (int k = 0; k < 32; ++k) wo[k] *= inv;
    }
}

// ---------------------------------------------------------------------------
// x (fp32) -> bf16
// ---------------------------------------------------------------------------
__global__ void convert_bf16_kernel(const float* __restrict__ src,
                                    unsigned short* __restrict__ dst, int n4)
{
    int v = blockIdx.x * 256 + threadIdx.x;
    if (v >= n4) return;
    float4 x = ((const float4*)src)[v];
    ushort4 o; o.x = f2bf(x.x); o.y = f2bf(x.y); o.z = f2bf(x.z); o.w = f2bf(x.w);
    ((ushort4*)dst)[v] = o;
}

// ---------------------------------------------------------------------------
// zero-init fp32 buffer (d_out is poisoned 0xAA before every call)
// ---------------------------------------------------------------------------
__global__ void zero_kernel(float4* __restrict__ p, int n4)
{
    int v = blockIdx.x * 256 + threadIdx.x;
    if (v < n4){ float4 z = {0.f,0.f,0.f,0.f}; p[v] = z; }
}

// ---------------------------------------------------------------------------
// Natural gather: dst[d, k*64+r] = scale_k * src[idx_k, d, r]
// ---------------------------------------------------------------------------
__global__ void gather_nat_kernel(const float* __restrict__ src,
                                  unsigned short* __restrict__ dst,
                                  const int* __restrict__ idx,
                                  const float* __restrict__ w,
                                  int Drows, int use_scale, int n4)
{
    int v = blockIdx.x * 256 + threadIdx.x;  // float4 index
    if (v >= n4) return;
    int c4 = v & 511;          // 512 float4 per dst row (2048 cols)
    int d  = v >> 9;
    int k  = c4 >> 4;          // expert slot 0..31
    int r4 = c4 & 15;          // float4 within r-dim (64)
    int p  = idx[k];
    float sc = use_scale ? w[k] : 1.0f;
    const float4* s = (const float4*)(src + ((size_t)p * Drows + d) * 64) + r4;
    float4 x = *s;
    ushort4 o;
    o.x = f2bf(sc * x.x); o.y = f2bf(sc * x.y);
    o.z = f2bf(sc * x.z); o.w = f2bf(sc * x.w);
    *(ushort4*)(dst + (size_t)d * 2048 + k * 64 + r4 * 4) = o;
}

// ---------------------------------------------------------------------------
// Transposed gather: dst[f, k*64+r] = scale_k * src[idx_k, r, f]
// ---------------------------------------------------------------------------
__global__ void gather_tr_kernel(const float* __restrict__ src,
                                 unsigned short* __restrict__ dst,
                                 const int* __restrict__ idx,
                                 const float* __restrict__ w,
                                 int Fcols, int use_scale)
{
    const int k  = blockIdx.y;
    const int f0 = blockIdx.x * 64;
    const int p  = idx[k];
    const float sc = use_scale ? w[k] : 1.0f;
    __shared__ float tile[64][65];
    const int t  = threadIdx.x;       // 256
    const int cf = t & 15;            // float4 column
    const int r0 = t >> 4;            // 16 rows per pass
    #pragma unroll
    for (int pass = 0; pass < 4; ++pass){
        int r = r0 + pass * 16;
        float4 x = *((const float4*)(src + ((size_t)p * 64 + r) * Fcols + f0) + cf);
        tile[r][cf * 4 + 0] = x.x; tile[r][cf * 4 + 1] = x.y;
        tile[r][cf * 4 + 2] = x.z; tile[r][cf * 4 + 3] = x.w;
    }
    __syncthreads();
    const int r4  = t & 15;           // float4 within r-dim
    const int fl0 = t >> 4;
    #pragma unroll
    for (int pass = 0; pass < 4; ++pass){
        int fl = fl0 + pass * 16;
        ushort4 o;
        o.x = f2bf(sc * tile[r4 * 4 + 0][fl]);
        o.y = f2bf(sc * tile[r4 * 4 + 1][fl]);
        o.z = f2bf(sc * tile[r4 * 4 + 2][fl]);
        o.w = f2bf(sc * tile[r4 * 4 + 3][fl]);
        *(ushort4*)(dst + (size_t)(f0 + fl) * 2048 + k * 64 + r4 * 4) = o;
    }
}

// ---------------------------------------------------------------------------
// NT bf16 GEMM: C(M,N) = A(M,K) * Bt(N,K)^T, fp32 accumulate.
// 128x128 block tile, BK=32, 4 waves each 64x64 via 4x4 mfma_16x16x32_bf16.
// Staging via global_load_lds width=16 (m97 pattern).
// EPI: 0 = bf16 store, 1 = gelu+bf16, 2 = fp32 store, 3 = fp32 atomicAdd.
// Split-K over gridDim.z: each z-slice accumulates Kslice of K.
// ---------------------------------------------------------------------------
template<int EPI>
__launch_bounds__(256, 2)
__global__ void gemm_nt_kernel(const unsigned short* __restrict__ A,
                               const unsigned short* __restrict__ Bt,
                               void* __restrict__ Cout,
                               int M, int N, int K, int Kslice)
{
    __shared__ unsigned short sA[128 * 32];
    __shared__ unsigned short sB[128 * 32];
    const int bm = blockIdx.y * 128;
    const int bn = blockIdx.x * 128;
    const int t    = threadIdx.x;
    const int wave = t >> 6;
    const int lane = t & 63;
    const int wr   = (wave >> 1) * 64;   // wave row offset in tile
    const int wc   = (wave & 1) * 64;    // wave col offset in tile
    const int m16  = lane & 15;
    const int quad = lane >> 4;
    const int srow = t >> 2;             // staging row (64 rows/pass)
    const int scol = t & 3;              // staging 16B chunk within 64B row

    f32x4 acc[4][4];
    const f32x4 z = {0.f, 0.f, 0.f, 0.f};
    #pragma unroll
    for (int i = 0; i < 4; ++i)
        #pragma unroll
        for (int j = 0; j < 4; ++j) acc[i][j] = z;

    const int kbeg = blockIdx.z * Kslice;
    const unsigned short* Arow = A  + (size_t)(bm + srow) * K + scol * 8 + kbeg;
    const unsigned short* Brow = Bt + (size_t)(bn + srow) * K + scol * 8 + kbeg;
    unsigned short* lA = sA + srow * 32 + scol * 8;   // byte off == t*16
    unsigned short* lB = sB + srow * 32 + scol * 8;

    for (int k0 = 0; k0 < Kslice; k0 += 32){
        async_lds16(Arow + k0,                    lA);
        async_lds16(Arow + (size_t)64 * K + k0,   lA + 64 * 32);
        async_lds16(Brow + k0,                    lB);
        async_lds16(Brow + (size_t)64 * K + k0,   lB + 64 * 32);
        __syncthreads();

        bhalf8 af[4], bfr[4];
        #pragma unroll
        for (int i = 0; i < 4; ++i)
            af[i] = *(const bhalf8*)(sA + (wr + i * 16 + m16) * 32 + quad * 8);
        #pragma unroll
        for (int j = 0; j < 4; ++j)
            bfr[j] = *(const bhalf8*)(sB + (wc + j * 16 + m16) * 32 + quad * 8);

        #pragma unroll
        for (int i = 0; i < 4; ++i)
            #pragma unroll
            for (int j = 0; j < 4; ++j)
                acc[i][j] = __builtin_amdgcn_mfma_f32_16x16x32_bf16(af[i], bfr[j], acc[i][j], 0, 0, 0);
        __syncthreads();
    }

    // Epilogue. C/D layout: col = lane&15, row = quad*4 + reg  [m89/m91]
    #pragma unroll
    for (int i = 0; i < 4; ++i){
        #pragma unroll
        for (int j = 0; j < 4; ++j){
            #pragma unroll
            for (int r = 0; r < 4; ++r){
                int row = bm + wr + i * 16 + quad * 4 + r;
                int col = bn + wc + j * 16 + m16;
                float vv = acc[i][j][r];
                if (EPI == 1) vv = gelu_tanh(vv);
                if (EPI == 2)      ((float*)Cout)[(size_t)row * N + col] = vv;
                else if (EPI == 3) atomicAdd(&((float*)Cout)[(size_t)row * N + col], vv);
                else ((unsigned short*)Cout)[(size_t)row * N + col] = f2bf(vv);
            }
        }
    }
}

// ---------------------------------------------------------------------------
extern "C" void kernel_launch(void* const* d_in, const int* in_sizes, int n_in,
                              void* d_out, int out_size, void* d_ws, size_t ws_size,
                              hipStream_t stream)
{
    const float* x    = (const float*)d_in[0];   // (2,1024,1024)
    const float* fc1A = (const float*)d_in[1];   // (256,1024,64)
    const float* fc1B = (const float*)d_in[2];   // (256,64,4096)
    const float* fc2A = (const float*)d_in[3];   // (256,4096,64)
    const float* fc2B = (const float*)d_in[4];   // (256,64,1024)
    const float* lg1  = (const float*)d_in[5];   // (256,)
    const float* lg2  = (const float*)d_in[6];   // (256,)
    float* out = (float*)d_out;                  // (2,1024,1024) fp32

    char* ws = (char*)d_ws;
    int*            idxb = (int*)(ws + 0);                    // [64]
    float*          wb   = (float*)(ws + 256);                // [64]
    unsigned short* x16  = (unsigned short*)(ws + 4096);                      // 4 MB  (2048x1024)
    unsigned short* Ag1  = (unsigned short*)(ws + 4096 + (4u << 20));         // 4 MB  (1024x2048)
    unsigned short* Bt1  = (unsigned short*)(ws + 4096 + (8u << 20));         // 16 MB (4096x2048)
    unsigned short* W1t  = (unsigned short*)(ws + 4096 + (24u << 20));        // 8 MB  (4096x1024)
    unsigned short* hbuf = (unsigned short*)(ws + 4096 + (32u << 20));        // 16 MB (2048x4096)
    unsigned short* Ag2  = Bt1;   // reuse: dead after GEMM1 (4096x2048)
    unsigned short* Bg2t = Ag1;   // reuse: dead after GEMM1 (1024x2048)
    unsigned short* W2t  = W1t;   // reuse: W1t dead after GEMM2 (1024x4096)

    // 0. zero d_out (GEMM4 accumulates into it atomically); 8 MB
    zero_kernel<<<dim3(2048), dim3(256), 0, stream>>>((float4*)out, 524288);

    // 1. top-k + softmax for both layers
    topk_softmax_kernel<<<dim3(2), dim3(64), 0, stream>>>(lg1, lg2, idxb, wb);

    // 2. x -> bf16
    convert_bf16_kernel<<<dim3(2048), dim3(256), 0, stream>>>(x, x16, 524288);

    // 3. gathers for layer 1
    gather_nat_kernel<<<dim3(2048), dim3(256), 0, stream>>>(fc1A, Ag1, idxb, wb, 1024, 1, 524288);
    gather_tr_kernel<<<dim3(64, 32), dim3(256), 0, stream>>>(fc1B, Bt1, idxb, wb, 4096, 0);

    // 4. GEMM1: W1t(4096x1024) = Bt1(4096x2048) * Ag1(1024x2048)^T
    gemm_nt_kernel<0><<<dim3(8, 32), dim3(256), 0, stream>>>(Bt1, Ag1, W1t, 4096, 1024, 2048, 2048);

    // 5. GEMM2: h(2048x4096) = gelu( x16(2048x1024) * W1t(4096x1024)^T )
    gemm_nt_kernel<1><<<dim3(32, 16), dim3(256), 0, stream>>>(x16, W1t, hbuf, 2048, 4096, 1024, 1024);

    // 6. gathers for layer 2
    gather_nat_kernel<<<dim3(8192), dim3(256), 0, stream>>>(fc2A, Ag2, idxb + 32, wb + 32, 4096, 0, 2097152);
    gather_tr_kernel<<<dim3(16, 32), dim3(256), 0, stream>>>(fc2B, Bg2t, idxb + 32, wb + 32, 1024, 1);

    // 7. GEMM3: W2t(1024x4096) = Bg2t(1024x2048) * Ag2(4096x2048)^T
    gemm_nt_kernel<0><<<dim3(32, 8), dim3(256), 0, stream>>>(Bg2t, Ag2, W2t, 1024, 4096, 2048, 2048);

    // 8. GEMM4: out(2048x1024) = h(2048x4096) * W2t(1024x4096)^T, split-K=4 atomic
    gemm_nt_kernel<3><<<dim3(8, 16, 4), dim3(256), 0, stream>>>(hbuf, W2t, out, 2048, 1024, 4096, 1024);
}

// Round 3
// 614.501 us; speedup vs baseline: 1.1380x; 1.0816x over previous
//
#include <hip/hip_runtime.h>
#include <cstdint>
#include <cstddef>

typedef __attribute__((ext_vector_type(8))) short bhalf8;   // 8 bf16 in 4 VGPRs
typedef __attribute__((ext_vector_type(4))) float f32x4;

__device__ __forceinline__ unsigned short f2bf(float f){
    unsigned int u = __float_as_uint(f);
    u += 0x7fffu + ((u >> 16) & 1u);          // round-to-nearest-even
    return (unsigned short)(u >> 16);
}

__device__ __forceinline__ float gelu_tanh(float x){
    const float c0 = 0.7978845608028654f;      // sqrt(2/pi)
    float x3 = x * x * x;
    float t = tanhf(c0 * (x + 0.044715f * x3));
    return 0.5f * x * (1.0f + t);
}

// async global->LDS, 16B per lane; LDS dest must be wave-uniform base + lane*16.
__device__ __forceinline__ void async_lds16(const unsigned short* g, unsigned short* l){
    __builtin_amdgcn_global_load_lds(
        (const __attribute__((address_space(1))) void*)g,
        (__attribute__((address_space(3))) void*)l, 16, 0, 0);
}

// ---------------------------------------------------------------------------
// Top-k(32) of 256 logits + softmax weights.
// ---------------------------------------------------------------------------
__global__ void topk_softmax_kernel(const float* __restrict__ lg1,
                                    const float* __restrict__ lg2,
                                    int* __restrict__ idx_out,
                                    float* __restrict__ w_out)
{
    const float* lg = (blockIdx.x == 0) ? lg1 : lg2;
    int*   idxo = idx_out + blockIdx.x * 32;
    float* wo   = w_out   + blockIdx.x * 32;
    const int lane = threadIdx.x;       // 0..63
    float v[4];
    #pragma unroll
    for (int j = 0; j < 4; ++j) v[j] = lg[lane * 4 + j];
    __shared__ float svals[32];
    for (int k = 0; k < 32; ++k){
        float bv = -1e30f; int bi = 0;
        #pragma unroll
        for (int j = 0; j < 4; ++j){
            if (v[j] > bv){ bv = v[j]; bi = lane * 4 + j; }
        }
        for (int off = 32; off > 0; off >>= 1){
            float ov = __shfl_down(bv, off);
            int   oi = __shfl_down(bi, off);
            if (ov > bv){ bv = ov; bi = oi; }
        }
        bv = __shfl(bv, 0);
        bi = __shfl(bi, 0);
        if (lane == 0){ svals[k] = bv; idxo[k] = bi; }
        if ((bi >> 2) == lane) v[bi & 3] = -1e30f;
    }
    if (lane == 0){
        float mx = svals[0];
        float sum = 0.f;
        for (int k = 0; k < 32; ++k){ float e = expf(svals[k] - mx); wo[k] = e; sum += e; }
        float inv = 1.f / sum;
        for (int k = 0; k < 32; ++k) wo[k] *= inv;
    }
}

// ---------------------------------------------------------------------------
// Fused: blocks [0,2048) convert x->bf16; blocks [2048,4096) zero d_out.
// ---------------------------------------------------------------------------
__global__ void prep_kernel(const float* __restrict__ src,
                            unsigned short* __restrict__ dst,
                            float4* __restrict__ outz)
{
    int b = blockIdx.x;
    if (b < 2048){
        int v = b * 256 + threadIdx.x;
        float4 x = ((const float4*)src)[v];
        ushort4 o; o.x = f2bf(x.x); o.y = f2bf(x.y); o.z = f2bf(x.z); o.w = f2bf(x.w);
        ((ushort4*)dst)[v] = o;
    } else {
        int v = (b - 2048) * 256 + threadIdx.x;
        float4 z = {0.f,0.f,0.f,0.f};
        outz[v] = z;
    }
}

// ---------------------------------------------------------------------------
// Natural gather: dst[d, k*64+r] = scale_k * src[idx_k, d, r]
// ---------------------------------------------------------------------------
__global__ void gather_nat_kernel(const float* __restrict__ src,
                                  unsigned short* __restrict__ dst,
                                  const int* __restrict__ idx,
                                  const float* __restrict__ w,
                                  int Drows, int use_scale, int n4)
{
    int v = blockIdx.x * 256 + threadIdx.x;  // float4 index
    if (v >= n4) return;
    int c4 = v & 511;          // 512 float4 per dst row (2048 cols)
    int d  = v >> 9;
    int k  = c4 >> 4;          // expert slot 0..31
    int r4 = c4 & 15;          // float4 within r-dim (64)
    int p  = idx[k];
    float sc = use_scale ? w[k] : 1.0f;
    const float4* s = (const float4*)(src + ((size_t)p * Drows + d) * 64) + r4;
    float4 x = *s;
    ushort4 o;
    o.x = f2bf(sc * x.x); o.y = f2bf(sc * x.y);
    o.z = f2bf(sc * x.z); o.w = f2bf(sc * x.w);
    *(ushort4*)(dst + (size_t)d * 2048 + k * 64 + r4 * 4) = o;
}

// ---------------------------------------------------------------------------
// Transposed gather: dst[f, k*64+r] = scale_k * src[idx_k, r, f]
// ---------------------------------------------------------------------------
__global__ void gather_tr_kernel(const float* __restrict__ src,
                                 unsigned short* __restrict__ dst,
                                 const int* __restrict__ idx,
                                 const float* __restrict__ w,
                                 int Fcols, int use_scale)
{
    const int k  = blockIdx.y;
    const int f0 = blockIdx.x * 64;
    const int p  = idx[k];
    const float sc = use_scale ? w[k] : 1.0f;
    __shared__ float tile[64][65];
    const int t  = threadIdx.x;       // 256
    const int cf = t & 15;
    const int r0 = t >> 4;
    #pragma unroll
    for (int pass = 0; pass < 4; ++pass){
        int r = r0 + pass * 16;
        float4 x = *((const float4*)(src + ((size_t)p * 64 + r) * Fcols + f0) + cf);
        tile[r][cf * 4 + 0] = x.x; tile[r][cf * 4 + 1] = x.y;
        tile[r][cf * 4 + 2] = x.z; tile[r][cf * 4 + 3] = x.w;
    }
    __syncthreads();
    const int r4  = t & 15;
    const int fl0 = t >> 4;
    #pragma unroll
    for (int pass = 0; pass < 4; ++pass){
        int fl = fl0 + pass * 16;
        ushort4 o;
        o.x = f2bf(sc * tile[r4 * 4 + 0][fl]);
        o.y = f2bf(sc * tile[r4 * 4 + 1][fl]);
        o.z = f2bf(sc * tile[r4 * 4 + 2][fl]);
        o.w = f2bf(sc * tile[r4 * 4 + 3][fl]);
        *(ushort4*)(dst + (size_t)(f0 + fl) * 2048 + k * 64 + r4 * 4) = o;
    }
}

// ---------------------------------------------------------------------------
// NT bf16 GEMM body: C(M,N) = A(M,K)*Bt(N,K)^T, fp32 acc, 128x128 tile.
// BK=64 as two conflict-free BK=32 stages in 4 separate 8KB LDS buffers
// (global_load_lds forbids padding; monolithic 128B rows would 4-way
// conflict the ds_read_b128s). One barrier pair per 32 MFMAs.
// EPI: 0 bf16, 1 gelu+bf16, 3 fp32 atomicAdd.
// ---------------------------------------------------------------------------
template<int EPI>
__device__ __forceinline__ void gemm_body(unsigned short* smem,
                                          const unsigned short* __restrict__ A,
                                          const unsigned short* __restrict__ Bt,
                                          void* __restrict__ Cout,
                                          int N, int K, int Kslice, int kbeg,
                                          int bm, int bn)
{
    unsigned short* sA0 = smem;
    unsigned short* sA1 = smem + 4096;
    unsigned short* sB0 = smem + 8192;
    unsigned short* sB1 = smem + 12288;
    const int t    = threadIdx.x;
    const int wave = t >> 6;
    const int lane = t & 63;
    const int wr   = (wave >> 1) * 64;
    const int wc   = (wave & 1) * 64;
    const int m16  = lane & 15;
    const int quad = lane >> 4;
    const int srow = t >> 2;             // 64 rows per staging pass
    const int scol = t & 3;              // 16B chunk within 64B (BK=32) row

    f32x4 acc[4][4];
    const f32x4 z = {0.f, 0.f, 0.f, 0.f};
    #pragma unroll
    for (int i = 0; i < 4; ++i)
        #pragma unroll
        for (int j = 0; j < 4; ++j) acc[i][j] = z;

    const unsigned short* Arow = A  + (size_t)(bm + srow) * K + scol * 8 + kbeg;
    const unsigned short* Brow = Bt + (size_t)(bn + srow) * K + scol * 8 + kbeg;
    const size_t rstep = (size_t)64 * K;
    unsigned short* lA0 = sA0 + t * 8;   // byte offset == t*16 in each buffer
    unsigned short* lA1 = sA1 + t * 8;
    unsigned short* lB0 = sB0 + t * 8;
    unsigned short* lB1 = sB1 + t * 8;

    for (int k0 = 0; k0 < Kslice; k0 += 64){
        async_lds16(Arow + k0,              lA0);
        async_lds16(Arow + rstep + k0,      lA0 + 64 * 32);
        async_lds16(Arow + k0 + 32,         lA1);
        async_lds16(Arow + rstep + k0 + 32, lA1 + 64 * 32);
        async_lds16(Brow + k0,              lB0);
        async_lds16(Brow + rstep + k0,      lB0 + 64 * 32);
        async_lds16(Brow + k0 + 32,         lB1);
        async_lds16(Brow + rstep + k0 + 32, lB1 + 64 * 32);
        __syncthreads();

        bhalf8 af0[4], bf0[4], af1[4], bf1[4];
        #pragma unroll
        for (int i = 0; i < 4; ++i){
            af0[i] = *(const bhalf8*)(sA0 + (wr + i * 16 + m16) * 32 + quad * 8);
            af1[i] = *(const bhalf8*)(sA1 + (wr + i * 16 + m16) * 32 + quad * 8);
        }
        #pragma unroll
        for (int j = 0; j < 4; ++j){
            bf0[j] = *(const bhalf8*)(sB0 + (wc + j * 16 + m16) * 32 + quad * 8);
            bf1[j] = *(const bhalf8*)(sB1 + (wc + j * 16 + m16) * 32 + quad * 8);
        }

        #pragma unroll
        for (int i = 0; i < 4; ++i)
            #pragma unroll
            for (int j = 0; j < 4; ++j)
                acc[i][j] = __builtin_amdgcn_mfma_f32_16x16x32_bf16(af0[i], bf0[j], acc[i][j], 0, 0, 0);
        #pragma unroll
        for (int i = 0; i < 4; ++i)
            #pragma unroll
            for (int j = 0; j < 4; ++j)
                acc[i][j] = __builtin_amdgcn_mfma_f32_16x16x32_bf16(af1[i], bf1[j], acc[i][j], 0, 0, 0);
        __syncthreads();
    }

    // Epilogue. C/D layout: col = lane&15, row = quad*4 + reg  [m89/m91]
    #pragma unroll
    for (int i = 0; i < 4; ++i){
        #pragma unroll
        for (int j = 0; j < 4; ++j){
            #pragma unroll
            for (int r = 0; r < 4; ++r){
                int row = bm + wr + i * 16 + quad * 4 + r;
                int col = bn + wc + j * 16 + m16;
                float vv = acc[i][j][r];
                if (EPI == 1) vv = gelu_tanh(vv);
                if (EPI == 3) atomicAdd(&((float*)Cout)[(size_t)row * N + col], vv);
                else ((unsigned short*)Cout)[(size_t)row * N + col] = f2bf(vv);
            }
        }
    }
}

// GEMM1 (W1t = Bt1 * Ag1^T, 4096x1024) and GEMM3 (W2t = Bg2t * Ag2^T,
// 1024x4096) fused into one 512-block launch: both K=2048, independent.
__launch_bounds__(256, 2)
__global__ void gemm13_kernel(const unsigned short* __restrict__ A1,
                              const unsigned short* __restrict__ B1,
                              unsigned short* __restrict__ C1,
                              const unsigned short* __restrict__ A2,
                              const unsigned short* __restrict__ B2,
                              unsigned short* __restrict__ C2)
{
    __shared__ unsigned short smem[4 * 128 * 32];
    int id = blockIdx.x;
    if (id < 256){
        gemm_body<0>(smem, A1, B1, C1, 1024, 2048, 2048, 0,
                     (id >> 3) * 128, (id & 7) * 128);
    } else {
        id -= 256;
        gemm_body<0>(smem, A2, B2, C2, 4096, 2048, 2048, 0,
                     (id >> 5) * 128, (id & 31) * 128);
    }
}

template<int EPI>
__launch_bounds__(256, 2)
__global__ void gemm_nt_kernel(const unsigned short* __restrict__ A,
                               const unsigned short* __restrict__ Bt,
                               void* __restrict__ Cout,
                               int N, int K, int Kslice)
{
    __shared__ unsigned short smem[4 * 128 * 32];
    gemm_body<EPI>(smem, A, Bt, Cout, N, K, Kslice, blockIdx.z * Kslice,
                   blockIdx.y * 128, blockIdx.x * 128);
}

// ---------------------------------------------------------------------------
extern "C" void kernel_launch(void* const* d_in, const int* in_sizes, int n_in,
                              void* d_out, int out_size, void* d_ws, size_t ws_size,
                              hipStream_t stream)
{
    const float* x    = (const float*)d_in[0];   // (2,1024,1024)
    const float* fc1A = (const float*)d_in[1];   // (256,1024,64)
    const float* fc1B = (const float*)d_in[2];   // (256,64,4096)
    const float* fc2A = (const float*)d_in[3];   // (256,4096,64)
    const float* fc2B = (const float*)d_in[4];   // (256,64,1024)
    const float* lg1  = (const float*)d_in[5];   // (256,)
    const float* lg2  = (const float*)d_in[6];   // (256,)
    float* out = (float*)d_out;                  // (2,1024,1024) fp32

    char* ws = (char*)d_ws;
    int*            idxb = (int*)(ws + 0);
    float*          wb   = (float*)(ws + 256);
    char* base = ws + 4096;
    unsigned short* x16  = (unsigned short*)(base);                  // 4 MB  (2048x1024)
    unsigned short* Ag1  = (unsigned short*)(base + (4ull  << 20));  // 4 MB  (1024x2048)
    unsigned short* Bt1  = (unsigned short*)(base + (8ull  << 20));  // 16 MB (4096x2048)
    unsigned short* Ag2  = (unsigned short*)(base + (24ull << 20));  // 16 MB (4096x2048)
    unsigned short* Bg2t = (unsigned short*)(base + (40ull << 20));  // 4 MB  (1024x2048)
    unsigned short* W1t  = (unsigned short*)(base + (44ull << 20));  // 8 MB  (4096x1024)
    unsigned short* W2t  = (unsigned short*)(base + (52ull << 20));  // 8 MB  (1024x4096)
    unsigned short* hbuf = (unsigned short*)(base + (60ull << 20));  // 16 MB (2048x4096)

    // 1. top-k + softmax
    topk_softmax_kernel<<<dim3(2), dim3(64), 0, stream>>>(lg1, lg2, idxb, wb);

    // 2. convert x->bf16 + zero d_out (GEMM4 atomics accumulate into it)
    prep_kernel<<<dim3(4096), dim3(256), 0, stream>>>(x, x16, (float4*)out);

    // 3. all four gathers (layer 1 and layer 2)
    gather_nat_kernel<<<dim3(2048), dim3(256), 0, stream>>>(fc1A, Ag1, idxb, wb, 1024, 1, 524288);
    gather_tr_kernel<<<dim3(64, 32), dim3(256), 0, stream>>>(fc1B, Bt1, idxb, wb, 4096, 0);
    gather_nat_kernel<<<dim3(8192), dim3(256), 0, stream>>>(fc2A, Ag2, idxb + 32, wb + 32, 4096, 0, 2097152);
    gather_tr_kernel<<<dim3(16, 32), dim3(256), 0, stream>>>(fc2B, Bg2t, idxb + 32, wb + 32, 1024, 1);

    // 4. GEMM1+GEMM3 fused (512 blocks, 2/CU)
    gemm13_kernel<<<dim3(512), dim3(256), 0, stream>>>(Bt1, Ag1, W1t, Bg2t, Ag2, W2t);

    // 5. GEMM2: h(2048x4096) = gelu( x16 * W1t^T )
    gemm_nt_kernel<1><<<dim3(32, 16), dim3(256), 0, stream>>>(x16, W1t, hbuf, 4096, 1024, 1024);

    // 6. GEMM4: out(2048x1024) = hbuf * W2t^T, split-K=4 atomic fp32
    gemm_nt_kernel<3><<<dim3(8, 16, 4), dim3(256), 0, stream>>>(hbuf, W2t, out, 1024, 4096, 1024);
}